// Round 11
// baseline (69.338 us; speedup 1.0000x reference)
//
#include <hip/hip_runtime.h>

// Problem geometry
#define HSZ 256
#define WSZ 256
#define BC  16          // b*c
#define NCH 64          // 8x8 window channels
#define HW  (HSZ * WSZ)
#define PADLO 3         // reflect pad (3,4)

// Plane-major + burst-drain tiling: block = (image b, channel-block mb,
// 8-row stripe ys). 256 threads = 4 waves. Two phases (g4=0,1); in each,
// wave wv computes output row y0+g4*4+wv (full 256 px, 16 ch) into a 64 KB
// LDS buffer; after barrier, wave wv drains channels 4wv..4wv+3 as
// 4 KB contiguous nontemporal bursts (1 KB per store instruction).
#define SR 8            // stripe rows per block
#define NTHR 256
#define TR (SR + 7)     // 15 halo rows
#define TC (WSZ + 7)    // 263 halo cols
#define TSTRIDE 264     // padded LDS tile stride (floats)
#define CHP 1024        // buf channel pitch (4 rows x 256 px floats)

typedef short bf16x8 __attribute__((ext_vector_type(8)));
typedef float f32x4  __attribute__((ext_vector_type(4)));

__device__ __forceinline__ int reflect_idx(int i) {
    i = (i < 0) ? -i : i;
    i = (i >= HSZ) ? (2 * (HSZ - 1) - i) : i;
    return i;
}

// fp32 -> bf16 RNE
__device__ __forceinline__ unsigned short f2bf(float f) {
    unsigned u = __builtin_bit_cast(unsigned, f);
    u += 0x7FFFu + ((u >> 16) & 1u);
    return (unsigned short)(u >> 16);
}

// ---------------------------------------------------------------------------
// Kernel 1 (R9-validated fast build): A = prod_i (I - 2 v_i v_i^T/||v_i||^2).
// ws layout: ushort frags[4][2][64][8]  (8 KB)
// ---------------------------------------------------------------------------
__global__ void build_A_frags(const float* __restrict__ v,
                              unsigned short* __restrict__ frags) {
    __shared__ float vs[64][64];
    __shared__ float rs[64];
    __shared__ float As[64][64];

    const int t = threadIdx.x;
    const int w = t >> 6;
    const int l = t & 63;
    const int r = (w << 4) | (l & 15);
    const int q = l >> 4;

    for (int idx = t; idx < 64 * 64; idx += NTHR)
        ((float*)vs)[idx] = v[idx];
    __syncthreads();

    if (t < 64) {
        const f32x4* vp = (const f32x4*)vs[t];
        float ss[4] = {0, 0, 0, 0};
#pragma unroll
        for (int c = 0; c < 16; ++c) {
            f32x4 vq = vp[c];
            ss[c & 3] = fmaf(vq[0], vq[0], ss[c & 3]);
            ss[c & 3] = fmaf(vq[1], vq[1], ss[c & 3]);
            ss[c & 3] = fmaf(vq[2], vq[2], ss[c & 3]);
            ss[c & 3] = fmaf(vq[3], vq[3], ss[c & 3]);
        }
        rs[t] = 2.0f / ((ss[0] + ss[1]) + (ss[2] + ss[3]));
    }

    float row[16];
#pragma unroll
    for (int c = 0; c < 16; ++c) row[c] = (q * 16 + c == r) ? 1.0f : 0.0f;

    __syncthreads();

    const f32x4* vq0 = (const f32x4*)&vs[0][q * 16];
    f32x4 nv0 = vq0[0], nv1 = vq0[1], nv2 = vq0[2], nv3 = vq0[3];
    float nrs = rs[0];

    for (int i = 0; i < 64; ++i) {
        f32x4 c0 = nv0, c1 = nv1, c2 = nv2, c3 = nv3;
        const float rcur = nrs;
        if (i < 63) {
            const f32x4* vqn = (const f32x4*)&vs[i + 1][q * 16];
            nv0 = vqn[0]; nv1 = vqn[1]; nv2 = vqn[2]; nv3 = vqn[3];
            nrs = rs[i + 1];
        }
        float vv[16];
#pragma unroll
        for (int j = 0; j < 4; ++j) { vv[j] = c0[j]; vv[4+j] = c1[j]; vv[8+j] = c2[j]; vv[12+j] = c3[j]; }

        float a0 = 0, a1 = 0, a2 = 0, a3 = 0;
#pragma unroll
        for (int c = 0; c < 4; ++c) {
            a0 = fmaf(row[c],      vv[c],      a0);
            a1 = fmaf(row[4 + c],  vv[4 + c],  a1);
            a2 = fmaf(row[8 + c],  vv[8 + c],  a2);
            a3 = fmaf(row[12 + c], vv[12 + c], a3);
        }
        float av = (a0 + a1) + (a2 + a3);
        av += __shfl_xor(av, 16);
        av += __shfl_xor(av, 32);

        const float scale = av * rcur;
#pragma unroll
        for (int c = 0; c < 16; ++c) row[c] = fmaf(-scale, vv[c], row[c]);
    }
#pragma unroll
    for (int c = 0; c < 16; ++c) As[r][q * 16 + c] = row[c];
    __syncthreads();

    const int ln = l & 15, lh = l >> 4;
    const int mb = w;
#pragma unroll
    for (int c2 = 0; c2 < 2; ++c2)
#pragma unroll
        for (int j = 0; j < 8; ++j) {
            float val = As[c2 * 32 + lh * 8 + j][mb * 16 + ln];
            frags[(((mb * 2 + c2) * 64) + l) * 8 + j] = f2bf(val);
        }
}

// ---------------------------------------------------------------------------
// Kernel 2: plane-major + per-channel burst drain.
// ---------------------------------------------------------------------------
__global__ __launch_bounds__(256)
void ortho_mfma_drain(const float* __restrict__ x,
                      const unsigned short* __restrict__ frags,
                      float* __restrict__ out) {
    __shared__ float tile[TR][TSTRIDE];    // 15.8 KB
    __shared__ float buf[16 * CHP];        // 64 KB: [ch 0..15][row 0..3][px 0..255]

    // XCD-bijective swizzle: 2048 blocks, 8 XCDs; XCD k gets lids
    // [k*256,(k+1)*256) = 2 whole images (input L2-local, output contiguous).
    const int bid = blockIdx.x;
    const int lid = (bid & 7) * 256 + (bid >> 3);
    const int b   = lid >> 7;          // /128: image
    const int rem = lid & 127;
    const int mb  = rem >> 5;          // channel-block 0..3
    const int ys  = rem & 31;          // row stripe 0..31
    const int y0  = ys * SR;

    const float* __restrict__ xb = x + (size_t)b * HW;

    const int tx = threadIdx.x;   // lane 0..63
    const int wv = threadIdx.y;   // wave 0..3
    const int tid = wv * 64 + tx;

    // Stage halo stripe (15 x 263) with reflect padding; linear, coalesced.
    for (int idx = tid; idx < TR * TC; idx += NTHR) {
        const int r = idx / TC;
        const int c = idx - r * TC;
        tile[r][c] = xb[(size_t)reflect_idx(y0 + r - PADLO) * WSZ + reflect_idx(c - PADLO)];
    }

    const int ln = tx & 15, lh = tx >> 4;

    // A fragments for this block's mb (2 x 16B)
    const bf16x8 af0 = *(const bf16x8*)(frags + ((mb * 2 + 0) * 64 + tx) * 8);
    const bf16x8 af1 = *(const bf16x8*)(frags + ((mb * 2 + 1) * 64 + tx) * 8);

    __syncthreads();

    float* __restrict__ outmb = out + (size_t)(b * NCH + mb * 16) * HW;

#pragma unroll
    for (int g4 = 0; g4 < 2; ++g4) {
        // Wave wv computes output row y0 + g4*4 + wv (4 consecutive rows/phase)
        const int tyr = g4 * 4 + wv;

        f32x4 acc[4][4];   // [qq][g]
#pragma unroll
        for (int qq = 0; qq < 4; ++qq) {
            // 16 consecutive fp32 per k-chunk -> bf16 (R4-verified path)
            unsigned short bfv[2][16];
#pragma unroll
            for (int c = 0; c < 2; ++c) {
                const f32x4* rp = (const f32x4*)&tile[tyr + 4 * c + lh][64 * qq + 4 * ln];
                f32x4 q0 = rp[0], q1 = rp[1], q2 = rp[2], q3 = rp[3];
                float fl[16];
#pragma unroll
                for (int j = 0; j < 4; ++j) { fl[j] = q0[j]; fl[4+j] = q1[j]; fl[8+j] = q2[j]; fl[12+j] = q3[j]; }
#pragma unroll
                for (int j = 0; j < 16; ++j) bfv[c][j] = f2bf(fl[j]);
            }
            bf16x8 bfrag[2][4];
#pragma unroll
            for (int c = 0; c < 2; ++c)
#pragma unroll
                for (int g = 0; g < 4; ++g)
#pragma unroll
                    for (int j = 0; j < 8; ++j)
                        bfrag[c][g][j] = (short)bfv[c][g + j];

#pragma unroll
            for (int g = 0; g < 4; ++g) {
                acc[qq][g] = (f32x4){0.0f, 0.0f, 0.0f, 0.0f};
                acc[qq][g] = __builtin_amdgcn_mfma_f32_16x16x32_bf16(af0, bfrag[0][g], acc[qq][g], 0, 0, 0);
                acc[qq][g] = __builtin_amdgcn_mfma_f32_16x16x32_bf16(af1, bfrag[1][g], acc[qq][g], 0, 0, 0);
            }
        }

        // Scatter results to buf: channel ch = lh*4 + r, row-in-group = wv,
        // px = 64*qq + 4*ln + g.
#pragma unroll
        for (int qq = 0; qq < 4; ++qq)
#pragma unroll
            for (int r = 0; r < 4; ++r) {
                f32x4 vv = { acc[qq][0][r], acc[qq][1][r], acc[qq][2][r], acc[qq][3][r] };
                *(f32x4*)&buf[(lh * 4 + r) * CHP + wv * 256 + 64 * qq + 4 * ln] = vv;
            }

        __syncthreads();

        // Drain: wave wv owns channels 4wv..4wv+3. Per channel: 4 consecutive
        // rows x 1 KB store instruction = 4 KB contiguous nontemporal burst.
        const int ybase = y0 + g4 * 4;
#pragma unroll
        for (int c = 0; c < 4; ++c) {
            const int ch = wv * 4 + c;
            float* __restrict__ outc = outmb + (size_t)ch * HW;
#pragma unroll
            for (int row = 0; row < 4; ++row) {
                f32x4 vv = *(const f32x4*)&buf[ch * CHP + row * 256 + 4 * tx];
                __builtin_nontemporal_store(
                    vv, (f32x4*)&outc[(size_t)(ybase + row) * WSZ + 4 * tx]);
            }
        }

        if (g4 == 0) __syncthreads();   // buf reused next phase
    }
}

// ---------------------------------------------------------------------------
extern "C" void kernel_launch(void* const* d_in, const int* in_sizes, int n_in,
                              void* d_out, int out_size, void* d_ws, size_t ws_size,
                              hipStream_t stream) {
    const float* x = (const float*)d_in[0];        // [2,8,256,256] fp32
    const float* v = (const float*)d_in[1];        // [64,64] fp32
    float* outp = (float*)d_out;                   // [16,64,256,256] fp32
    unsigned short* frags = (unsigned short*)d_ws; // 4*2*64*8 bf16 = 8 KB

    build_A_frags<<<1, 256, 0, stream>>>(v, frags);

    dim3 grid(BC * 4 * (HSZ / SR));                // 16*4*32 = 2048 blocks
    dim3 block(64, 4);                             // 256 threads = 4 waves
    ortho_mfma_drain<<<grid, block, 0, stream>>>(x, frags, outp);
}

// Round 12
// 67.547 us; speedup vs baseline: 1.0265x; 1.0265x over previous
//
#include <hip/hip_runtime.h>

// Problem geometry
#define HSZ 256
#define WSZ 256
#define BC  16          // b*c
#define NCH 64          // 8x8 window channels
#define HW  (HSZ * WSZ)
#define PADLO 3         // reflect pad (3,4)

// Plane-major tiling: block = (image b, channel-block mb, 8-row stripe ys).
// 256 threads = 4 waves; wave wv computes rows y0+2wv, y0+2wv+1 (full 256 px,
// 16 channels). 2048 blocks; __launch_bounds__(256,5) caps VGPR for 5 waves/SIMD.
#define SR 8            // stripe rows per block
#define NTHR 256
#define TR (SR + 7)     // 15 halo rows
#define TC (WSZ + 7)    // 263 halo cols
#define TSTRIDE 264     // padded LDS row stride (floats)

typedef short bf16x8 __attribute__((ext_vector_type(8)));
typedef float f32x4  __attribute__((ext_vector_type(4)));

__device__ __forceinline__ int reflect_idx(int i) {
    i = (i < 0) ? -i : i;
    i = (i >= HSZ) ? (2 * (HSZ - 1) - i) : i;
    return i;
}

// fp32 -> bf16 RNE
__device__ __forceinline__ unsigned short f2bf(float f) {
    unsigned u = __builtin_bit_cast(unsigned, f);
    u += 0x7FFFu + ((u >> 16) & 1u);
    return (unsigned short)(u >> 16);
}

// ---------------------------------------------------------------------------
// Kernel 1 (R9-validated fast build): A = prod_i (I - 2 v_i v_i^T/||v_i||^2).
// v staged in LDS; 2/||v_i||^2 precomputed; next-iter register prefetch.
// Wave w emits bf16 A-fragments for m-block mb=w:
//   frag(mb,c): lane l, elem j = A[k = c*32 + (l>>4)*8 + j][mb*16 + (l&15)]
// ws layout: ushort frags[4][2][64][8]  (8 KB)
// ---------------------------------------------------------------------------
__global__ void build_A_frags(const float* __restrict__ v,
                              unsigned short* __restrict__ frags) {
    __shared__ float vs[64][64];
    __shared__ float rs[64];
    __shared__ float As[64][64];

    const int t = threadIdx.x;
    const int w = t >> 6;
    const int l = t & 63;
    const int r = (w << 4) | (l & 15);
    const int q = l >> 4;

    for (int idx = t; idx < 64 * 64; idx += NTHR)
        ((float*)vs)[idx] = v[idx];
    __syncthreads();

    if (t < 64) {
        const f32x4* vp = (const f32x4*)vs[t];
        float ss[4] = {0, 0, 0, 0};
#pragma unroll
        for (int c = 0; c < 16; ++c) {
            f32x4 vq = vp[c];
            ss[c & 3] = fmaf(vq[0], vq[0], ss[c & 3]);
            ss[c & 3] = fmaf(vq[1], vq[1], ss[c & 3]);
            ss[c & 3] = fmaf(vq[2], vq[2], ss[c & 3]);
            ss[c & 3] = fmaf(vq[3], vq[3], ss[c & 3]);
        }
        rs[t] = 2.0f / ((ss[0] + ss[1]) + (ss[2] + ss[3]));
    }

    float row[16];
#pragma unroll
    for (int c = 0; c < 16; ++c) row[c] = (q * 16 + c == r) ? 1.0f : 0.0f;

    __syncthreads();

    const f32x4* vq0 = (const f32x4*)&vs[0][q * 16];
    f32x4 nv0 = vq0[0], nv1 = vq0[1], nv2 = vq0[2], nv3 = vq0[3];
    float nrs = rs[0];

    for (int i = 0; i < 64; ++i) {
        f32x4 c0 = nv0, c1 = nv1, c2 = nv2, c3 = nv3;
        const float rcur = nrs;
        if (i < 63) {
            const f32x4* vqn = (const f32x4*)&vs[i + 1][q * 16];
            nv0 = vqn[0]; nv1 = vqn[1]; nv2 = vqn[2]; nv3 = vqn[3];
            nrs = rs[i + 1];
        }
        float vv[16];
#pragma unroll
        for (int j = 0; j < 4; ++j) { vv[j] = c0[j]; vv[4+j] = c1[j]; vv[8+j] = c2[j]; vv[12+j] = c3[j]; }

        float a0 = 0, a1 = 0, a2 = 0, a3 = 0;
#pragma unroll
        for (int c = 0; c < 4; ++c) {
            a0 = fmaf(row[c],      vv[c],      a0);
            a1 = fmaf(row[4 + c],  vv[4 + c],  a1);
            a2 = fmaf(row[8 + c],  vv[8 + c],  a2);
            a3 = fmaf(row[12 + c], vv[12 + c], a3);
        }
        float av = (a0 + a1) + (a2 + a3);
        av += __shfl_xor(av, 16);
        av += __shfl_xor(av, 32);

        const float scale = av * rcur;
#pragma unroll
        for (int c = 0; c < 16; ++c) row[c] = fmaf(-scale, vv[c], row[c]);
    }
#pragma unroll
    for (int c = 0; c < 16; ++c) As[r][q * 16 + c] = row[c];
    __syncthreads();

    const int ln = l & 15, lh = l >> 4;
    const int mb = w;
#pragma unroll
    for (int c2 = 0; c2 < 2; ++c2)
#pragma unroll
        for (int j = 0; j < 8; ++j) {
            float val = As[c2 * 32 + lh * 8 + j][mb * 16 + ln];
            frags[(((mb * 2 + c2) * 64) + l) * 8 + j] = f2bf(val);
        }
}

// ---------------------------------------------------------------------------
// Kernel 2: plane-major, occupancy-tuned. Block (b, mb, ys): 16 ch x 8 rows
// x 256 px. Wave wv: rows y0+2wv..y0+2wv+1 over x-quarters qq. Plain cached
// stores (L2 write-back acks fast -> short WAR stalls on acc reuse); 5
// waves/SIMD via launch_bounds so stalled waves are hidden by siblings.
// ---------------------------------------------------------------------------
__global__ __launch_bounds__(256, 5)
void ortho_mfma_plane(const float* __restrict__ x,
                      const unsigned short* __restrict__ frags,
                      float* __restrict__ out) {
    __shared__ float tile[TR][TSTRIDE];   // 15 x 264 x 4B = 15.8 KB

    // XCD-bijective swizzle: 2048 blocks, 8 XCDs; XCD k gets lids
    // [k*256,(k+1)*256) = 2 whole images (input L2-local, output contiguous).
    const int bid = blockIdx.x;
    const int lid = (bid & 7) * 256 + (bid >> 3);
    const int b   = lid >> 7;          // /128: image
    const int rem = lid & 127;
    const int mb  = rem >> 5;          // channel-block 0..3
    const int ys  = rem & 31;          // row stripe 0..31
    const int y0  = ys * SR;

    const float* __restrict__ xb = x + (size_t)b * HW;

    const int tx = threadIdx.x;   // lane 0..63
    const int wv = threadIdx.y;   // wave 0..3
    const int tid = wv * 64 + tx;

    // Stage halo stripe (15 x 263) with reflect padding; linear, coalesced.
    for (int idx = tid; idx < TR * TC; idx += NTHR) {
        const int r = idx / TC;
        const int c = idx - r * TC;
        tile[r][c] = xb[(size_t)reflect_idx(y0 + r - PADLO) * WSZ + reflect_idx(c - PADLO)];
    }

    const int ln = tx & 15, lh = tx >> 4;

    // A fragments for this block's single mb (2 x 16B)
    const bf16x8 af0 = *(const bf16x8*)(frags + ((mb * 2 + 0) * 64 + tx) * 8);
    const bf16x8 af1 = *(const bf16x8*)(frags + ((mb * 2 + 1) * 64 + tx) * 8);

    __syncthreads();

    float* __restrict__ outp = out + (size_t)(b * NCH + mb * 16) * HW;

#pragma unroll
    for (int rr = 0; rr < 2; ++rr) {
        const int tyr = wv * 2 + rr;          // tile-relative output row
        const int y   = y0 + tyr;

#pragma unroll
        for (int qq = 0; qq < 4; ++qq) {
            // 12 consecutive fp32 per k-chunk (elems 0..10 used) -> bf16
            unsigned short bfv[2][12];
#pragma unroll
            for (int c = 0; c < 2; ++c) {
                const f32x4* rp = (const f32x4*)&tile[tyr + 4 * c + lh][64 * qq + 4 * ln];
                f32x4 q0 = rp[0], q1 = rp[1], q2 = rp[2];
                float fl[12];
#pragma unroll
                for (int j = 0; j < 4; ++j) { fl[j] = q0[j]; fl[4+j] = q1[j]; fl[8+j] = q2[j]; }
#pragma unroll
                for (int j = 0; j < 12; ++j) bfv[c][j] = f2bf(fl[j]);
            }

            // B fragments: chunk c, pixel-group g -> elems [g .. g+7]
            bf16x8 bfrag[2][4];
#pragma unroll
            for (int c = 0; c < 2; ++c)
#pragma unroll
                for (int g = 0; g < 4; ++g)
#pragma unroll
                    for (int j = 0; j < 8; ++j)
                        bfrag[c][g][j] = (short)bfv[c][g + j];

            f32x4 acc[4];
#pragma unroll
            for (int g = 0; g < 4; ++g) {
                acc[g] = (f32x4){0.0f, 0.0f, 0.0f, 0.0f};
                acc[g] = __builtin_amdgcn_mfma_f32_16x16x32_bf16(af0, bfrag[0][g], acc[g], 0, 0, 0);
                acc[g] = __builtin_amdgcn_mfma_f32_16x16x32_bf16(af1, bfrag[1][g], acc[g], 0, 0, 0);
            }

            // Store: ch-local = lh*4 + r; px = 64*qq + 4*ln + g. Plain stores.
#pragma unroll
            for (int r = 0; r < 4; ++r) {
                const int chl = lh * 4 + r;
                f32x4 vv = { acc[0][r], acc[1][r], acc[2][r], acc[3][r] };
                *(f32x4*)&outp[(size_t)chl * HW + (size_t)y * WSZ + 64 * qq + 4 * ln] = vv;
            }
        }
    }
}

// ---------------------------------------------------------------------------
extern "C" void kernel_launch(void* const* d_in, const int* in_sizes, int n_in,
                              void* d_out, int out_size, void* d_ws, size_t ws_size,
                              hipStream_t stream) {
    const float* x = (const float*)d_in[0];        // [2,8,256,256] fp32
    const float* v = (const float*)d_in[1];        // [64,64] fp32
    float* outp = (float*)d_out;                   // [16,64,256,256] fp32
    unsigned short* frags = (unsigned short*)d_ws; // 4*2*64*8 bf16 = 8 KB

    build_A_frags<<<1, 256, 0, stream>>>(v, frags);

    dim3 grid(BC * 4 * (HSZ / SR));                // 16*4*32 = 2048 blocks
    dim3 block(64, 4);                             // 256 threads = 4 waves
    ortho_mfma_plane<<<grid, block, 0, stream>>>(x, frags, outp);
}